// Round 1
// baseline (682.867 us; speedup 1.0000x reference)
//
#include <hip/hip_runtime.h>
#include <math.h>

#define NBINS 28
#define L2E 1.44269504088896340736f

// fast HW transcendentals (v_exp_f32 / v_rcp_f32), ~1 ulp
#if defined(__has_builtin)
#if __has_builtin(__builtin_amdgcn_exp2f)
#define EXP2F(x) __builtin_amdgcn_exp2f(x)
#endif
#if __has_builtin(__builtin_amdgcn_rcpf)
#define RCPF(x) __builtin_amdgcn_rcpf(x)
#endif
#endif
#ifndef EXP2F
#define EXP2F(x) exp2f(x)
#endif
#ifndef RCPF
#define RCPF(x) (1.0f / (x))
#endif

// workspace float offsets
#define WS_TBL 0    // 40 floats: ml_table[d-1] = exp(ml_mlp(d) - 0.25 d), d=1..40
#define WS_W1  64   // 128 floats, prescaled by -log2(e)
#define WS_B1  192  // 16
#define WS_W2  208  // 256, prescaled by -log2(e)
#define WS_B2  464  // 16
#define WS_W3  480  // 16, prescaled by +log2(e)
#define WS_B3  496  // 1

// One small block: build ml lookup table (40 entries), write dl2_scores into
// out_bins, and stage log2e-prescaled mh weights into workspace.
__global__ void prep_kernel(const float* __restrict__ mh_W1, const float* __restrict__ mh_b1,
                            const float* __restrict__ mh_W2, const float* __restrict__ mh_b2,
                            const float* __restrict__ mh_W3, const float* __restrict__ mh_b3,
                            const float* __restrict__ ml_W1, const float* __restrict__ ml_b1,
                            const float* __restrict__ ml_W2, const float* __restrict__ ml_b2,
                            const float* __restrict__ ml_W3, const float* __restrict__ ml_b3,
                            float* __restrict__ ws, float* __restrict__ out_bins) {
    const int t = threadIdx.x;  // 64 threads
    for (int k = t; k < 128; k += 64) ws[WS_W1 + k] = -L2E * mh_W1[k];
    for (int k = t; k < 16;  k += 64) ws[WS_B1 + k] = -L2E * mh_b1[k];
    for (int k = t; k < 256; k += 64) ws[WS_W2 + k] = -L2E * mh_W2[k];
    for (int k = t; k < 16;  k += 64) ws[WS_B2 + k] = -L2E * mh_b2[k];
    for (int k = t; k < 16;  k += 64) ws[WS_W3 + k] =  L2E * mh_W3[k];
    if (t == 0) ws[WS_B3] = L2E * mh_b3[0];

    if (t < 40) {
        const float x = (float)(t + 1);
        float h1[16], h2[16];
        #pragma unroll
        for (int j = 0; j < 16; ++j)
            h1[j] = 1.0f / (1.0f + expf(-(x * ml_W1[j] + ml_b1[j])));
        #pragma unroll
        for (int j = 0; j < 16; ++j) {
            float a = ml_b2[j];
            #pragma unroll
            for (int k = 0; k < 16; ++k) a = fmaf(h1[k], ml_W2[k * 16 + j], a);
            h2[j] = 1.0f / (1.0f + expf(-a));
        }
        float phi = ml_b3[0];
        #pragma unroll
        for (int k = 0; k < 16; ++k) phi = fmaf(h2[k], ml_W3[k], phi);
        const float sc = expf(phi - 0.25f * x);
        ws[WS_TBL + t] = sc;
        if (t < NBINS) out_bins[t] = sc;  // dl2_scores term of output 1
    }
}

__global__ __launch_bounds__(256) void main_kernel(
        const float* __restrict__ x_feat,
        const int* __restrict__ del_lens,
        const int* __restrict__ mh_len,
        const float* __restrict__ ws,
        float* __restrict__ out,
        float* __restrict__ out_bins,
        int n) {
    __shared__ float s_tbl[40];
    __shared__ float s_bins[4 * NBINS];
    const int tid = threadIdx.x;
    if (tid < 40) s_tbl[tid] = ws[WS_TBL + tid];
    if (tid < 4 * NBINS) s_bins[tid] = 0.0f;
    __syncthreads();

    const float4* __restrict__ x4 = reinterpret_cast<const float4*>(x_feat);
    const int stride = gridDim.x * blockDim.x;
    float* myb = &s_bins[(tid >> 6) * NBINS];

    for (int i = blockIdx.x * blockDim.x + tid; i < n; i += stride) {
        const float4 xa = x4[2 * i];
        const float4 xb = x4[2 * i + 1];
        const int dl = del_lens[i];
        const int ml = mh_len[i];

        float h1[16];
        #pragma unroll
        for (int j = 0; j < 16; ++j) {
            float a = ws[WS_B1 + j];
            a = fmaf(xa.x, ws[WS_W1 + 0 * 16 + j], a);
            a = fmaf(xa.y, ws[WS_W1 + 1 * 16 + j], a);
            a = fmaf(xa.z, ws[WS_W1 + 2 * 16 + j], a);
            a = fmaf(xa.w, ws[WS_W1 + 3 * 16 + j], a);
            a = fmaf(xb.x, ws[WS_W1 + 4 * 16 + j], a);
            a = fmaf(xb.y, ws[WS_W1 + 5 * 16 + j], a);
            a = fmaf(xb.z, ws[WS_W1 + 6 * 16 + j], a);
            a = fmaf(xb.w, ws[WS_W1 + 7 * 16 + j], a);
            h1[j] = RCPF(1.0f + EXP2F(a));   // sigmoid via prescaled weights
        }

        float h2[16];
        #pragma unroll
        for (int j = 0; j < 16; ++j) {
            float a = ws[WS_B2 + j];
            #pragma unroll
            for (int k = 0; k < 16; ++k) a = fmaf(h1[k], ws[WS_W2 + k * 16 + j], a);
            h2[j] = RCPF(1.0f + EXP2F(a));
        }

        float phi = ws[WS_B3];   // prescaled by +log2e
        #pragma unroll
        for (int k = 0; k < 16; ++k) phi = fmaf(h2[k], ws[WS_W3 + k], phi);

        const float sc = EXP2F(fmaf((float)dl, -0.25f * L2E, phi));  // mh_scores[i]

        const int ti = min(max(dl, 1), 40) - 1;
        const float add = (dl == ml) ? s_tbl[ti] : 0.0f;
        out[i] = sc + add;                       // y_mh_phi[i]

        if (dl >= 1 && dl <= NBINS) unsafeAtomicAdd(&myb[dl - 1], sc);
    }

    __syncthreads();
    if (tid < NBINS) {
        const float v = s_bins[tid] + s_bins[NBINS + tid] +
                        s_bins[2 * NBINS + tid] + s_bins[3 * NBINS + tid];
        unsafeAtomicAdd(&out_bins[tid], v);
    }
}

extern "C" void kernel_launch(void* const* d_in, const int* in_sizes, int n_in,
                              void* d_out, int out_size, void* d_ws, size_t ws_size,
                              hipStream_t stream) {
    const int n = in_sizes[0] / 8;

    const float* x_feat = (const float*)d_in[0];
    const float* mh_W1  = (const float*)d_in[1];
    const float* mh_b1  = (const float*)d_in[2];
    const float* mh_W2  = (const float*)d_in[3];
    const float* mh_b2  = (const float*)d_in[4];
    const float* mh_W3  = (const float*)d_in[5];
    const float* mh_b3  = (const float*)d_in[6];
    const float* ml_W1  = (const float*)d_in[7];
    const float* ml_b1  = (const float*)d_in[8];
    const float* ml_W2  = (const float*)d_in[9];
    const float* ml_b2  = (const float*)d_in[10];
    const float* ml_W3  = (const float*)d_in[11];
    const float* ml_b3  = (const float*)d_in[12];
    const int* del_lens = (const int*)d_in[13];
    const int* mh_len   = (const int*)d_in[14];

    float* out      = (float*)d_out;
    float* out_bins = out + n;        // last 28 elements of d_out
    float* ws       = (float*)d_ws;

    prep_kernel<<<dim3(1), dim3(64), 0, stream>>>(
        mh_W1, mh_b1, mh_W2, mh_b2, mh_W3, mh_b3,
        ml_W1, ml_b1, ml_W2, ml_b2, ml_W3, ml_b3,
        ws, out_bins);

    main_kernel<<<dim3(2048), dim3(256), 0, stream>>>(
        x_feat, del_lens, mh_len, ws, out, out_bins, n);
}